// Round 2
// baseline (117.513 us; speedup 1.0000x reference)
//
#include <hip/hip_runtime.h>

#define MAXL 33
#define SIGMA_DIS 3.0f
#define PB 128  // blocks per batch image

// ---------------------------------------------------------------------------
// Kernel 1: per-(batch,label) segmented sum of sq = sum_c pred^2 and counts.
// pred [B, C=4, N] f32, labels [B, N] i32. Each thread handles 4 pixels/iter
// (float4 per channel + int4 labels), accumulates into a per-block LDS
// histogram, then writes NON-ATOMIC per-block partials to d_ws (slot-major:
// partial[(b*66 + s) * PB + blockIdx.x]) — no global atomic contention.
// ---------------------------------------------------------------------------
__global__ __launch_bounds__(256) void seg_hist_kernel(
    const float* __restrict__ pred, const int* __restrict__ labels,
    float* __restrict__ partial, int N) {
  const int b = blockIdx.y;
  const int ng = N >> 2;  // float4 groups per image
  __shared__ float h_ssq[MAXL];
  __shared__ float h_cnt[MAXL];
  const int tid = threadIdx.x;
  if (tid < MAXL) {
    h_ssq[tid] = 0.f;
    h_cnt[tid] = 0.f;
  }
  __syncthreads();

  const float4* p = reinterpret_cast<const float4*>(pred) + (size_t)b * 4 * ng;
  const int4* lb = reinterpret_cast<const int4*>(labels) + (size_t)b * ng;

  for (int g = blockIdx.x * blockDim.x + tid; g < ng; g += PB * blockDim.x) {
    float4 c0 = p[g];
    float4 c1 = p[g + ng];
    float4 c2 = p[g + 2 * ng];
    float4 c3 = p[g + 3 * ng];
    int4 l = lb[g];
    float s0 = c0.x * c0.x + c1.x * c1.x + c2.x * c2.x + c3.x * c3.x;
    float s1 = c0.y * c0.y + c1.y * c1.y + c2.y * c2.y + c3.y * c3.y;
    float s2 = c0.z * c0.z + c1.z * c1.z + c2.z * c2.z + c3.z * c3.z;
    float s3 = c0.w * c0.w + c1.w * c1.w + c2.w * c2.w + c3.w * c3.w;
    atomicAdd(&h_ssq[l.x], s0);
    atomicAdd(&h_cnt[l.x], 1.f);
    atomicAdd(&h_ssq[l.y], s1);
    atomicAdd(&h_cnt[l.y], 1.f);
    atomicAdd(&h_ssq[l.z], s2);
    atomicAdd(&h_cnt[l.z], 1.f);
    atomicAdd(&h_ssq[l.w], s3);
    atomicAdd(&h_cnt[l.w], 1.f);
  }
  __syncthreads();
  if (tid < 2 * MAXL) {
    float v = (tid < MAXL) ? h_ssq[tid] : h_cnt[tid - MAXL];
    partial[(size_t)(b * 2 * MAXL + tid) * PB + blockIdx.x] = v;
  }
}

// ---------------------------------------------------------------------------
// Kernel 2 (1 block, 512 threads): tree-reduce partials (528 slots x PB),
// then s = ssq/card^2, nk = max present label, and the pairwise log-loss.
// ---------------------------------------------------------------------------
__global__ __launch_bounds__(512) void reduce_finalize_kernel(
    const float* __restrict__ partial, float* __restrict__ out) {
  __shared__ float red[8 * 2 * MAXL];   // [b*66 + s]: s<33 ssq, s>=33 cnt
  __shared__ float s_val[8 * MAXL];
  __shared__ float s_flag[8 * MAXL];
  __shared__ float s_invden[8];
  __shared__ float s_part[8];
  const int tid = threadIdx.x;
  const int wave = tid >> 6;
  const int lane = tid & 63;

  // Each of 8 waves reduces slots round-robin; PB=128 -> 2 floats per lane.
  for (int slot = wave; slot < 8 * 2 * MAXL; slot += 8) {
    const float* src = partial + (size_t)slot * PB;
    float v = src[lane * 2] + src[lane * 2 + 1];
    for (int off = 32; off; off >>= 1) v += __shfl_down(v, off, 64);
    if (lane == 0) red[slot] = v;
  }
  __syncthreads();

  for (int i = tid; i < 8 * MAXL; i += 512) {
    int b = i / MAXL, l = i - b * MAXL;
    float cnt = red[b * 2 * MAXL + MAXL + l];
    float ssq = red[b * 2 * MAXL + l];
    float safe = cnt > 0.f ? cnt : 1.f;
    s_val[i] = ssq / (safe * safe);
    s_flag[i] = (l >= 1 && cnt > 0.f) ? 1.f : 0.f;
  }
  __syncthreads();
  if (tid < 8) {
    int nk = 0;
    for (int l = MAXL - 1; l >= 0; --l) {
      if (red[tid * 2 * MAXL + MAXL + l] > 0.f) {
        nk = l;
        break;
      }
    }
    s_invden[tid] = (nk > 1) ? 1.f / ((float)nk * ((float)nk - 1.f)) : 0.f;
  }
  __syncthreads();

  float local = 0.f;
  const int total = 8 * MAXL * MAXL;
  for (int idx = tid; idx < total; idx += 512) {
    int b = idx / (MAXL * MAXL);
    int r = idx - b * MAXL * MAXL;
    int i = r / MAXL;
    int j = r - i * MAXL;
    if (i < j && s_flag[b * MAXL + i] != 0.f && s_flag[b * MAXL + j] != 0.f) {
      float S = s_val[b * MAXL + i] + s_val[b * MAXL + j];
      float d = SIGMA_DIS - sqrtf(S);
      local += logf(d * d + 1.f) * s_invden[b];
    }
  }
  for (int off = 32; off; off >>= 1) local += __shfl_down(local, off, 64);
  if (lane == 0) s_part[wave] = local;
  __syncthreads();
  if (tid == 0) {
    float tot = 0.f;
    for (int w = 0; w < 8; ++w) tot += s_part[w];
    out[0] = tot;
  }
}

extern "C" void kernel_launch(void* const* d_in, const int* in_sizes, int n_in,
                              void* d_out, int out_size, void* d_ws,
                              size_t ws_size, hipStream_t stream) {
  const float* pred = (const float*)d_in[0];
  // d_in[1] = kernels_mask: unused by the reference math -> never read.
  const int* labels = (const int*)d_in[2];
  float* out = (float*)d_out;

  const int B = 8;
  const int N = in_sizes[2] / B;  // 896*896 = 802816, divisible by 4

  float* partial = (float*)d_ws;  // 528 slots x PB floats = 270 KB

  dim3 grid(PB, B);  // 1024 blocks, grid-stride over N/4 groups
  seg_hist_kernel<<<grid, dim3(256), 0, stream>>>(pred, labels, partial, N);
  reduce_finalize_kernel<<<dim3(1), dim3(512), 0, stream>>>(partial, out);
}

// Round 3
// 82.839 us; speedup vs baseline: 1.4186x; 1.4186x over previous
//
#include <hip/hip_runtime.h>

#define MAXL 33
#define SIGMA_DIS 3.0f
#define PB 128  // blocks per batch image

// ---------------------------------------------------------------------------
// Kernel 1: per-(batch,label) segmented sum of sq = sum_c pred^2 and counts.
// pred [B, C=4, N] f32, labels [B, N] i32. Each thread handles 4 pixels/iter
// (float4 per channel + int4 labels). Accumulation into PER-WAVE private LDS
// histograms using NATIVE LDS atomics: ds_add_u32 for counts (int atomicAdd)
// and ds_add_f32 for float sums (unsafeAtomicAdd) — the default float
// atomicAdd lowers to a CAS retry loop, which was the 80 us bottleneck.
// Non-atomic per-block partials go to d_ws (slot-major).
// ---------------------------------------------------------------------------
__global__ __launch_bounds__(256) void seg_hist_kernel(
    const float* __restrict__ pred, const int* __restrict__ labels,
    float* __restrict__ partial, int N) {
  const int b = blockIdx.y;
  const int ng = N >> 2;  // float4 groups per image
  __shared__ float h_ssq[4][MAXL];     // per-wave private
  __shared__ unsigned h_cnt[4][MAXL];  // per-wave private
  const int tid = threadIdx.x;
  const int wave = tid >> 6;
  for (int i = tid; i < 4 * MAXL; i += 256) {
    (&h_ssq[0][0])[i] = 0.f;
    (&h_cnt[0][0])[i] = 0u;
  }
  __syncthreads();

  const float4* p = reinterpret_cast<const float4*>(pred) + (size_t)b * 4 * ng;
  const int4* lb = reinterpret_cast<const int4*>(labels) + (size_t)b * ng;

  float* ws = h_ssq[wave];
  unsigned* wc = h_cnt[wave];
  for (int g = blockIdx.x * blockDim.x + tid; g < ng; g += PB * blockDim.x) {
    float4 c0 = p[g];
    float4 c1 = p[g + ng];
    float4 c2 = p[g + 2 * ng];
    float4 c3 = p[g + 3 * ng];
    int4 l = lb[g];
    float s0 = c0.x * c0.x + c1.x * c1.x + c2.x * c2.x + c3.x * c3.x;
    float s1 = c0.y * c0.y + c1.y * c1.y + c2.y * c2.y + c3.y * c3.y;
    float s2 = c0.z * c0.z + c1.z * c1.z + c2.z * c2.z + c3.z * c3.z;
    float s3 = c0.w * c0.w + c1.w * c1.w + c2.w * c2.w + c3.w * c3.w;
    unsafeAtomicAdd(&ws[l.x], s0);
    atomicAdd(&wc[l.x], 1u);
    unsafeAtomicAdd(&ws[l.y], s1);
    atomicAdd(&wc[l.y], 1u);
    unsafeAtomicAdd(&ws[l.z], s2);
    atomicAdd(&wc[l.z], 1u);
    unsafeAtomicAdd(&ws[l.w], s3);
    atomicAdd(&wc[l.w], 1u);
  }
  __syncthreads();
  if (tid < MAXL) {
    float ssq = h_ssq[0][tid] + h_ssq[1][tid] + h_ssq[2][tid] + h_ssq[3][tid];
    float cnt = (float)(h_cnt[0][tid] + h_cnt[1][tid] + h_cnt[2][tid] +
                        h_cnt[3][tid]);
    partial[(size_t)(b * 2 * MAXL + tid) * PB + blockIdx.x] = ssq;
    partial[(size_t)(b * 2 * MAXL + MAXL + tid) * PB + blockIdx.x] = cnt;
  }
}

// ---------------------------------------------------------------------------
// Kernel 2 (1 block, 512 threads): tree-reduce partials (528 slots x PB),
// then s = ssq/card^2, nk = max present label, and the pairwise log-loss.
// ---------------------------------------------------------------------------
__global__ __launch_bounds__(512) void reduce_finalize_kernel(
    const float* __restrict__ partial, float* __restrict__ out) {
  __shared__ float red[8 * 2 * MAXL];  // [b*66 + s]: s<33 ssq, s>=33 cnt
  __shared__ float s_val[8 * MAXL];
  __shared__ float s_flag[8 * MAXL];
  __shared__ float s_invden[8];
  __shared__ float s_part[8];
  const int tid = threadIdx.x;
  const int wave = tid >> 6;
  const int lane = tid & 63;

  // Each of 8 waves reduces slots round-robin; PB=128 -> 2 floats per lane.
  for (int slot = wave; slot < 8 * 2 * MAXL; slot += 8) {
    const float* src = partial + (size_t)slot * PB;
    float v = src[lane * 2] + src[lane * 2 + 1];
    for (int off = 32; off; off >>= 1) v += __shfl_down(v, off, 64);
    if (lane == 0) red[slot] = v;
  }
  __syncthreads();

  for (int i = tid; i < 8 * MAXL; i += 512) {
    int b = i / MAXL, l = i - b * MAXL;
    float cnt = red[b * 2 * MAXL + MAXL + l];
    float ssq = red[b * 2 * MAXL + l];
    float safe = cnt > 0.f ? cnt : 1.f;
    s_val[i] = ssq / (safe * safe);
    s_flag[i] = (l >= 1 && cnt > 0.f) ? 1.f : 0.f;
  }
  __syncthreads();
  if (tid < 8) {
    int nk = 0;
    for (int l = MAXL - 1; l >= 0; --l) {
      if (red[tid * 2 * MAXL + MAXL + l] > 0.f) {
        nk = l;
        break;
      }
    }
    s_invden[tid] = (nk > 1) ? 1.f / ((float)nk * ((float)nk - 1.f)) : 0.f;
  }
  __syncthreads();

  float local = 0.f;
  const int total = 8 * MAXL * MAXL;
  for (int idx = tid; idx < total; idx += 512) {
    int b = idx / (MAXL * MAXL);
    int r = idx - b * MAXL * MAXL;
    int i = r / MAXL;
    int j = r - i * MAXL;
    if (i < j && s_flag[b * MAXL + i] != 0.f && s_flag[b * MAXL + j] != 0.f) {
      float S = s_val[b * MAXL + i] + s_val[b * MAXL + j];
      float d = SIGMA_DIS - sqrtf(S);
      local += logf(d * d + 1.f) * s_invden[b];
    }
  }
  for (int off = 32; off; off >>= 1) local += __shfl_down(local, off, 64);
  if (lane == 0) s_part[wave] = local;
  __syncthreads();
  if (tid == 0) {
    float tot = 0.f;
    for (int w = 0; w < 8; ++w) tot += s_part[w];
    out[0] = tot;
  }
}

extern "C" void kernel_launch(void* const* d_in, const int* in_sizes, int n_in,
                              void* d_out, int out_size, void* d_ws,
                              size_t ws_size, hipStream_t stream) {
  const float* pred = (const float*)d_in[0];
  // d_in[1] = kernels_mask: unused by the reference math -> never read.
  const int* labels = (const int*)d_in[2];
  float* out = (float*)d_out;

  const int B = 8;
  const int N = in_sizes[2] / B;  // 896*896 = 802816, divisible by 4

  float* partial = (float*)d_ws;  // 528 slots x PB floats = 270 KB

  dim3 grid(PB, B);  // 1024 blocks, grid-stride over N/4 groups
  seg_hist_kernel<<<grid, dim3(256), 0, stream>>>(pred, labels, partial, N);
  reduce_finalize_kernel<<<dim3(1), dim3(512), 0, stream>>>(partial, out);
}

// Round 4
// 48.407 us; speedup vs baseline: 2.4276x; 1.7113x over previous
//
#include <hip/hip_runtime.h>

#define MAXL 33
#define HSTRIDE 35  // per-thread hist stride in u64 entries (odd -> bank spread)
#define PB 128      // blocks per batch image
#define TPB 128     // threads per block

// ---------------------------------------------------------------------------
// Kernel 1: per-(batch,label) segmented sums WITHOUT any atomics.
// Each thread owns a private LDS histogram of 33 packed u64 entries:
//   low 32 bits  = f32 bit-pattern of the running sum of sq
//   high 32 bits = u32 pixel count
// Plain ds_read_b64 / ds_write_b64 RMW, sequential per pixel (program order
// makes same-thread duplicate labels safe). No LDS atomic serialization —
// that was the 58 us fixed cost (~2.8 cy per atomic lane-op at the LDS unit).
// Block flush: 2 waves tree-reduce the 128 thread-histograms, then write
// non-atomic per-block partials (slot-major) to d_ws.
// ---------------------------------------------------------------------------
__global__ __launch_bounds__(TPB, 2) void seg_hist_kernel(
    const float* __restrict__ pred, const int* __restrict__ labels,
    float* __restrict__ partial, int N) {
  const int b = blockIdx.y;
  const int ng = N >> 2;  // float4 groups per image
  __shared__ unsigned long long hist[TPB * HSTRIDE];  // 35.8 KB
  __shared__ float xred[2][2][MAXL];                  // [wave][{ssq,cnt}][bin]
  const int tid = threadIdx.x;

  unsigned long long* hp = &hist[tid * HSTRIDE];
#pragma unroll
  for (int i = 0; i < MAXL; ++i) hp[i] = 0ull;  // own slice; sync at flush

  const float4* p = reinterpret_cast<const float4*>(pred) + (size_t)b * 4 * ng;
  const int4* lb = reinterpret_cast<const int4*>(labels) + (size_t)b * ng;

  for (int g = blockIdx.x * TPB + tid; g < ng; g += PB * TPB) {
    float4 c0 = p[g];
    float4 c1 = p[g + ng];
    float4 c2 = p[g + 2 * ng];
    float4 c3 = p[g + 3 * ng];
    int4 l = lb[g];
    float s0 = c0.x * c0.x + c1.x * c1.x + c2.x * c2.x + c3.x * c3.x;
    float s1 = c0.y * c0.y + c1.y * c1.y + c2.y * c2.y + c3.y * c3.y;
    float s2 = c0.z * c0.z + c1.z * c1.z + c2.z * c2.z + c3.z * c3.z;
    float s3 = c0.w * c0.w + c1.w * c1.w + c2.w * c2.w + c3.w * c3.w;

    unsigned long long v;
    v = hp[l.x];
    hp[l.x] = ((v >> 32) + 1ull) << 32 |
              (unsigned)__float_as_uint(__uint_as_float((unsigned)v) + s0);
    v = hp[l.y];
    hp[l.y] = ((v >> 32) + 1ull) << 32 |
              (unsigned)__float_as_uint(__uint_as_float((unsigned)v) + s1);
    v = hp[l.z];
    hp[l.z] = ((v >> 32) + 1ull) << 32 |
              (unsigned)__float_as_uint(__uint_as_float((unsigned)v) + s2);
    v = hp[l.w];
    hp[l.w] = ((v >> 32) + 1ull) << 32 |
              (unsigned)__float_as_uint(__uint_as_float((unsigned)v) + s3);
  }
  __syncthreads();

  const int wave = tid >> 6;
  const int lane = tid & 63;
  if (lane < MAXL) {  // wave w sums thread-slices w*64 .. w*64+63 for bin=lane
    float fs = 0.f;
    unsigned fc = 0u;
    for (int u = 0; u < 64; ++u) {
      unsigned long long v = hist[(wave * 64 + u) * HSTRIDE + lane];
      fs += __uint_as_float((unsigned)v);
      fc += (unsigned)(v >> 32);
    }
    xred[wave][0][lane] = fs;
    xred[wave][1][lane] = (float)fc;
  }
  __syncthreads();
  if (tid < MAXL) {
    float ssq = xred[0][0][tid] + xred[1][0][tid];
    float cnt = xred[0][1][tid] + xred[1][1][tid];
    partial[(size_t)(b * 2 * MAXL + tid) * PB + blockIdx.x] = ssq;
    partial[(size_t)(b * 2 * MAXL + MAXL + tid) * PB + blockIdx.x] = cnt;
  }
}

// ---------------------------------------------------------------------------
// Kernel 2 (1 block, 512 threads): tree-reduce partials (528 slots x PB),
// batched 8 independent slot-loads per wave (hide global latency), then
// s = ssq/card^2, nk = max present label, pairwise log-loss.
// ---------------------------------------------------------------------------
__global__ __launch_bounds__(512) void reduce_finalize_kernel(
    const float* __restrict__ partial, float* __restrict__ out) {
  __shared__ float red[8 * 2 * MAXL];  // 528 slots
  __shared__ float s_val[8 * MAXL];
  __shared__ float s_flag[8 * MAXL];
  __shared__ float s_invden[8];
  __shared__ float s_part[8];
  const int tid = threadIdx.x;
  const int wave = tid >> 6;
  const int lane = tid & 63;

  // Each slot row = PB floats = 64 float2; lane loads one float2.
  const float2* src = reinterpret_cast<const float2*>(partial);
  for (int s0 = wave * 8; s0 < 8 * 2 * MAXL; s0 += 64) {
    float2 v[8];
#pragma unroll
    for (int u = 0; u < 8; ++u) v[u] = src[(size_t)(s0 + u) * (PB / 2) + lane];
#pragma unroll
    for (int u = 0; u < 8; ++u) {
      float t = v[u].x + v[u].y;
      for (int off = 32; off; off >>= 1) t += __shfl_down(t, off, 64);
      if (lane == 0) red[s0 + u] = t;
    }
  }
  __syncthreads();

  for (int i = tid; i < 8 * MAXL; i += 512) {
    int b = i / MAXL, l = i - b * MAXL;
    float cnt = red[b * 2 * MAXL + MAXL + l];
    float ssq = red[b * 2 * MAXL + l];
    float safe = cnt > 0.f ? cnt : 1.f;
    s_val[i] = ssq / (safe * safe);
    s_flag[i] = (l >= 1 && cnt > 0.f) ? 1.f : 0.f;
  }
  __syncthreads();
  if (tid < 8) {
    int nk = 0;
    for (int l = MAXL - 1; l >= 0; --l) {
      if (red[tid * 2 * MAXL + MAXL + l] > 0.f) {
        nk = l;
        break;
      }
    }
    s_invden[tid] = (nk > 1) ? 1.f / ((float)nk * ((float)nk - 1.f)) : 0.f;
  }
  __syncthreads();

  float local = 0.f;
  const int total = 8 * MAXL * MAXL;
  for (int idx = tid; idx < total; idx += 512) {
    int b = idx / (MAXL * MAXL);
    int r = idx - b * MAXL * MAXL;
    int i = r / MAXL;
    int j = r - i * MAXL;
    if (i < j && s_flag[b * MAXL + i] != 0.f && s_flag[b * MAXL + j] != 0.f) {
      float S = s_val[b * MAXL + i] + s_val[b * MAXL + j];
      float d = 3.0f - sqrtf(S);
      local += logf(d * d + 1.f) * s_invden[b];
    }
  }
  for (int off = 32; off; off >>= 1) local += __shfl_down(local, off, 64);
  if (lane == 0) s_part[wave] = local;
  __syncthreads();
  if (tid == 0) {
    float tot = 0.f;
    for (int w = 0; w < 8; ++w) tot += s_part[w];
    out[0] = tot;
  }
}

extern "C" void kernel_launch(void* const* d_in, const int* in_sizes, int n_in,
                              void* d_out, int out_size, void* d_ws,
                              size_t ws_size, hipStream_t stream) {
  const float* pred = (const float*)d_in[0];
  // d_in[1] = kernels_mask: unused by the reference math -> never read.
  const int* labels = (const int*)d_in[2];
  float* out = (float*)d_out;

  const int B = 8;
  const int N = in_sizes[2] / B;  // 896*896 = 802816, divisible by 4

  float* partial = (float*)d_ws;  // 528 slots x PB floats = 270 KB

  dim3 grid(PB, B);  // 1024 blocks of 128 threads, 4 blocks/CU
  seg_hist_kernel<<<grid, dim3(TPB), 0, stream>>>(pred, labels, partial, N);
  reduce_finalize_kernel<<<dim3(1), dim3(512), 0, stream>>>(partial, out);
}

// Round 5
// 39.250 us; speedup vs baseline: 2.9940x; 1.2333x over previous
//
#include <hip/hip_runtime.h>

#define MAXL 33
#define PB 128   // blocks per batch image
#define TPB 128  // threads per block

// ---------------------------------------------------------------------------
// Kernel 1: per-(batch,label) segmented sums, no atomics anywhere.
// Per-THREAD private LDS histograms, split into f32 sums and u32 counts with
// odd dword stride 33 (bank = (33*l + k) % 32 -> uniform over all 32 banks;
// the previous packed-u64 layout could only touch even banks = 4-way
// conflict). Per 4-pixel iteration: batch-read the 4 bins (ONE LDS
// round-trip instead of 4), merge duplicate labels in registers via pairwise
// eq-masks (writes issued in pixel order; DS pipe is in-order per wave, so
// the last write wins -> correct under label collisions), batch-write.
// Global loads are register double-buffered: next iteration's 5 loads issue
// before processing the current one, hiding HBM latency under VALU+LDS work.
// ---------------------------------------------------------------------------
__global__ __launch_bounds__(TPB, 2) void seg_hist_kernel(
    const float* __restrict__ pred, const int* __restrict__ labels,
    float* __restrict__ partial, int N) {
  const int b = blockIdx.y;
  const int ng = N >> 2;  // float4 groups per image
  __shared__ float sumh[TPB * MAXL];     // 16.9 KB
  __shared__ unsigned cnth[TPB * MAXL];  // 16.9 KB
  __shared__ float xred[2][2][MAXL];
  const int tid = threadIdx.x;

  float* sh = &sumh[tid * MAXL];
  unsigned* ch = &cnth[tid * MAXL];
#pragma unroll
  for (int i = 0; i < MAXL; ++i) {
    sh[i] = 0.f;
    ch[i] = 0u;
  }

  const float4* p = reinterpret_cast<const float4*>(pred) + (size_t)b * 4 * ng;
  const int4* lb = reinterpret_cast<const int4*>(labels) + (size_t)b * ng;
  const int STRIDE = PB * TPB;

  int g = blockIdx.x * TPB + tid;  // always < ng on first iter
  float4 c0 = p[g], c1 = p[g + ng], c2 = p[g + 2 * ng], c3 = p[g + 3 * ng];
  int4 l = lb[g];

  while (true) {
    const int gn = g + STRIDE;
    const bool more = gn < ng;
    float4 n0, n1, n2, n3;
    int4 nl;
    if (more) {  // prefetch next iteration
      n0 = p[gn];
      n1 = p[gn + ng];
      n2 = p[gn + 2 * ng];
      n3 = p[gn + 3 * ng];
      nl = lb[gn];
    }

    // per-pixel sum over channels
    float s0 = c0.x * c0.x + c1.x * c1.x + c2.x * c2.x + c3.x * c3.x;
    float s1 = c0.y * c0.y + c1.y * c1.y + c2.y * c2.y + c3.y * c3.y;
    float s2 = c0.z * c0.z + c1.z * c1.z + c2.z * c2.z + c3.z * c3.z;
    float s3 = c0.w * c0.w + c1.w * c1.w + c2.w * c2.w + c3.w * c3.w;

    // duplicate-label merge masks
    const bool e01 = l.x == l.y, e02 = l.x == l.z, e03 = l.x == l.w;
    const bool e12 = l.y == l.z, e13 = l.y == l.w, e23 = l.z == l.w;
    const float w1 = s1 + (e01 ? s0 : 0.f);
    const float w2 = s2 + (e12 ? s1 : 0.f) + (e02 ? s0 : 0.f);
    const float w3 =
        s3 + (e23 ? s2 : 0.f) + (e13 ? s1 : 0.f) + (e03 ? s0 : 0.f);
    const unsigned m1 = 1u + (unsigned)e01;
    const unsigned m2 = 1u + (unsigned)e12 + (unsigned)e02;
    const unsigned m3 = 1u + (unsigned)e23 + (unsigned)e13 + (unsigned)e03;

    // batched reads (one LDS round-trip), then ordered writes (last wins)
    const float r0 = sh[l.x], r1 = sh[l.y], r2 = sh[l.z], r3 = sh[l.w];
    const unsigned q0 = ch[l.x], q1 = ch[l.y], q2 = ch[l.z], q3 = ch[l.w];
    sh[l.x] = r0 + s0;
    sh[l.y] = r1 + w1;
    sh[l.z] = r2 + w2;
    sh[l.w] = r3 + w3;
    ch[l.x] = q0 + 1u;
    ch[l.y] = q1 + m1;
    ch[l.z] = q2 + m2;
    ch[l.w] = q3 + m3;

    if (!more) break;
    c0 = n0;
    c1 = n1;
    c2 = n2;
    c3 = n3;
    l = nl;
    g = gn;
  }
  __syncthreads();

  const int wave = tid >> 6;
  const int lane = tid & 63;
  if (lane < MAXL) {  // wave w reduces thread-slices w*64 .. w*64+63
    float fs = 0.f;
    unsigned fc = 0u;
#pragma unroll 8
    for (int u = 0; u < 64; ++u) {
      fs += sumh[(wave * 64 + u) * MAXL + lane];
      fc += cnth[(wave * 64 + u) * MAXL + lane];
    }
    xred[wave][0][lane] = fs;
    xred[wave][1][lane] = (float)fc;
  }
  __syncthreads();
  if (tid < MAXL) {
    partial[(size_t)(b * 2 * MAXL + tid) * PB + blockIdx.x] =
        xred[0][0][tid] + xred[1][0][tid];
    partial[(size_t)(b * 2 * MAXL + MAXL + tid) * PB + blockIdx.x] =
        xred[0][1][tid] + xred[1][1][tid];
  }
}

// ---------------------------------------------------------------------------
// Kernel 2 (1 block, 512 threads): slot-per-thread row sums of the partials
// (no shuffle chains, 32 independent float4 loads each), then
// s = ssq/card^2, nk = max present label, pairwise log-loss.
// ---------------------------------------------------------------------------
__global__ __launch_bounds__(512) void reduce_finalize_kernel(
    const float* __restrict__ partial, float* __restrict__ out) {
  __shared__ float red[8 * 2 * MAXL];  // 528 slots
  __shared__ float s_val[8 * MAXL];
  __shared__ float s_flag[8 * MAXL];
  __shared__ float s_invden[8];
  __shared__ float s_part[8];
  const int tid = threadIdx.x;
  const int wave = tid >> 6;
  const int lane = tid & 63;

  {
    int slot = tid;
    const float4* row =
        reinterpret_cast<const float4*>(partial) + (size_t)slot * (PB / 4);
    float a0 = 0.f, a1 = 0.f;
#pragma unroll 8
    for (int u = 0; u < PB / 4; u += 2) {
      float4 x = row[u], y = row[u + 1];
      a0 += x.x + x.y + x.z + x.w;
      a1 += y.x + y.y + y.z + y.w;
    }
    if (slot < 8 * 2 * MAXL) red[slot] = a0 + a1;
  }
  if (tid < 8 * 2 * MAXL - 512) {
    int slot = 512 + tid;
    const float4* row =
        reinterpret_cast<const float4*>(partial) + (size_t)slot * (PB / 4);
    float a0 = 0.f, a1 = 0.f;
#pragma unroll 8
    for (int u = 0; u < PB / 4; u += 2) {
      float4 x = row[u], y = row[u + 1];
      a0 += x.x + x.y + x.z + x.w;
      a1 += y.x + y.y + y.z + y.w;
    }
    red[slot] = a0 + a1;
  }
  __syncthreads();

  for (int i = tid; i < 8 * MAXL; i += 512) {
    int b = i / MAXL, l = i - b * MAXL;
    float cnt = red[b * 2 * MAXL + MAXL + l];
    float ssq = red[b * 2 * MAXL + l];
    float safe = cnt > 0.f ? cnt : 1.f;
    s_val[i] = ssq / (safe * safe);
    s_flag[i] = (l >= 1 && cnt > 0.f) ? 1.f : 0.f;
  }
  __syncthreads();
  if (tid < 8) {
    int nk = 0;
    for (int l = MAXL - 1; l >= 0; --l) {
      if (red[tid * 2 * MAXL + MAXL + l] > 0.f) {
        nk = l;
        break;
      }
    }
    s_invden[tid] = (nk > 1) ? 1.f / ((float)nk * ((float)nk - 1.f)) : 0.f;
  }
  __syncthreads();

  float local = 0.f;
  const int total = 8 * MAXL * MAXL;
  for (int idx = tid; idx < total; idx += 512) {
    int b = idx / (MAXL * MAXL);
    int r = idx - b * MAXL * MAXL;
    int i = r / MAXL;
    int j = r - i * MAXL;
    if (i < j && s_flag[b * MAXL + i] != 0.f && s_flag[b * MAXL + j] != 0.f) {
      float S = s_val[b * MAXL + i] + s_val[b * MAXL + j];
      float d = 3.0f - sqrtf(S);
      local += logf(d * d + 1.f) * s_invden[b];
    }
  }
  for (int off = 32; off; off >>= 1) local += __shfl_down(local, off, 64);
  if (lane == 0) s_part[wave] = local;
  __syncthreads();
  if (tid == 0) {
    float tot = 0.f;
    for (int w = 0; w < 8; ++w) tot += s_part[w];
    out[0] = tot;
  }
}

extern "C" void kernel_launch(void* const* d_in, const int* in_sizes, int n_in,
                              void* d_out, int out_size, void* d_ws,
                              size_t ws_size, hipStream_t stream) {
  const float* pred = (const float*)d_in[0];
  // d_in[1] = kernels_mask: unused by the reference math -> never read.
  const int* labels = (const int*)d_in[2];
  float* out = (float*)d_out;

  const int B = 8;
  const int N = in_sizes[2] / B;  // 896*896 = 802816, divisible by 4

  float* partial = (float*)d_ws;  // 528 slots x PB floats = 270 KB

  dim3 grid(PB, B);  // 1024 blocks of 128 threads, 4 blocks/CU
  seg_hist_kernel<<<grid, dim3(TPB), 0, stream>>>(pred, labels, partial, N);
  reduce_finalize_kernel<<<dim3(1), dim3(512), 0, stream>>>(partial, out);
}